// Round 6
// baseline (321.681 us; speedup 1.0000x reference)
//
#include <hip/hip_runtime.h>
#include <hip/hip_bf16.h>
#include <cstdint>
#include <cstddef>

// Problem shape (fixed): x [B=16][N=2048][D=512] fp32
#define BB 16
#define NN 2048
#define DD 512

typedef _Float16 f16x8 __attribute__((ext_vector_type(8)));
typedef _Float16 f16x4 __attribute__((ext_vector_type(4)));
typedef float f32x4 __attribute__((ext_vector_type(4)));

// Async global->LDS, 16 B per lane. LDS dest = wave-uniform base + lane*16.
__device__ __forceinline__ void async_ld16(void* lds, const void* g) {
    __builtin_amdgcn_global_load_lds(
        (const __attribute__((address_space(1))) unsigned int*)(uintptr_t)g,
        (__attribute__((address_space(3))) unsigned int*)(uint32_t)(uintptr_t)lds,
        16, 0, 0);
}

// ---------------------------------------------------------------------------
// K1 (fused, v2): read x once per 64-row slab.
//  - quarter-row threads: 2-shuffle ssq reduce -> rnorm
//  - xh  = fp16 cast (unnormalized), written inline from load regs
//  - vT  = fp16 transpose via XOR-swizzled LDS:
//      write: [jj][chunk ^ (jj&7)] b128 (8 lanes/bank-quad = even floor)
//      read : paired-column b32 (rows d,d+1 at once), 2 lanes/bank = free
// grid (NN/64, BB), 256 threads, LDS 64 KB -> 2 blocks/CU.
// ---------------------------------------------------------------------------
__global__ __launch_bounds__(256) void k_prep(const float* __restrict__ x,
                                              _Float16* __restrict__ xh,
                                              _Float16* __restrict__ vT,
                                              float* __restrict__ rnorm,
                                              float* __restrict__ denom) {
    __shared__ _Float16 t[64 * 512];     // [jj][chunk^(jj&7)], 8-half chunks
    const int tid = threadIdx.x;
    const int b = blockIdx.y, j0 = blockIdx.x * 64;
    if (tid < 64) denom[b * NN + j0 + tid] = 0.f;

    const int jj = tid >> 2, c = tid & 3;     // 4 lanes per row
    const int row = j0 + jj;
    const float* xr = x + ((size_t)b * NN + row) * DD;
    _Float16* xhr = xh + ((size_t)b * NN + row) * DD;
    float ss = 0.f;
    #pragma unroll
    for (int i = 0; i < 16; ++i) {
        const int d0 = c * 8 + 32 * i;        // interleaved quarter-row
        float4 lo = *(const float4*)(xr + d0);
        float4 hi = *(const float4*)(xr + d0 + 4);
        ss += lo.x*lo.x + lo.y*lo.y + lo.z*lo.z + lo.w*lo.w
            + hi.x*hi.x + hi.y*hi.y + hi.z*hi.z + hi.w*hi.w;
        f16x8 v = {(_Float16)lo.x, (_Float16)lo.y, (_Float16)lo.z, (_Float16)lo.w,
                   (_Float16)hi.x, (_Float16)hi.y, (_Float16)hi.z, (_Float16)hi.w};
        const int chunk = c + 4 * i;
        *(f16x8*)&t[jj * 512 + ((chunk ^ (jj & 7)) << 3)] = v;
        *(f16x8*)(xhr + d0) = v;              // quad = 64B contiguous
    }
    ss += __shfl_xor(ss, 1);
    ss += __shfl_xor(ss, 2);
    if (c == 0) rnorm[b * NN + row] = 1.0f / sqrtf(ss);
    __syncthreads();

    // vT gather: thread owns d-pair (2*tid, 2*tid+1), sweeps 64 j's.
    const int dp = tid;
    const uint32_t* tw = (const uint32_t*)t;
    _Float16* v0p = vT + ((size_t)b * DD + 2 * dp) * NN + j0;
    _Float16* v1p = v0p + NN;
    #pragma unroll
    for (int jc = 0; jc < 8; ++jc) {
        uint32_t lo[4], hi[4];
        #pragma unroll
        for (int r = 0; r < 4; ++r) {
            const int ja = jc * 8 + 2 * r, jb = ja + 1;
            const uint32_t ua = tw[ja * 256 + (((dp >> 2) ^ (ja & 7)) << 2) + (dp & 3)];
            const uint32_t ub = tw[jb * 256 + (((dp >> 2) ^ (jb & 7)) << 2) + (dp & 3)];
            lo[r] = (ua & 0xffffu) | (ub << 16);
            hi[r] = (ua >> 16) | (ub & 0xffff0000u);
        }
        *(uint4*)(v0p + jc * 8) = *(const uint4*)lo;
        *(uint4*)(v1p + jc * 8) = *(const uint4*)hi;
    }
}

// ---------------------------------------------------------------------------
// K2: W = exp( (xh xh^T) * rn_i * rn_j ), symmetric-triangular.
// GEMM: async swizzled staging, 128x128 block, 4 waves 64x64, BK=64.
// Epilogue: phase 1 col-major WtT (b64) -> coalesced W(J,I);
//           phase 2 (off-diag) row-major Wt pitch 130 -> coalesced W(I,J).
// ---------------------------------------------------------------------------
__global__ __launch_bounds__(256) void k_scores(const _Float16* __restrict__ xh,
                                                const float* __restrict__ rnorm,
                                                _Float16* __restrict__ W,
                                                float* __restrict__ denom) {
    __shared__ _Float16 smem[17408];          // As[8192] Bs[8192]; epi buffers
    __shared__ float rnI[128], rnJ[128];
    const int tid = threadIdx.x;
    const int lane = tid & 63, wv = tid >> 6;
    const int wr = wv >> 1, wc = wv & 1;
    const int m_ = lane & 15, quad = lane >> 4;
    const int b = blockIdx.z;

    int rem = blockIdx.x, ti = 0, rowlen = NN / 128;
    while (rem >= rowlen) { rem -= rowlen; ++ti; --rowlen; }
    const int tj = ti + rem;
    const int I = ti * 128, J = tj * 128;
    const bool diag = (ti == tj);

    const _Float16* Ab = xh + ((size_t)b * NN + I) * DD;
    const _Float16* Bb = xh + ((size_t)b * NN + J) * DD;
    if (tid < 128) rnI[tid] = rnorm[b * NN + I + tid];
    else           rnJ[tid - 128] = rnorm[b * NN + J + (tid - 128)];

    f32x4 acc[4][4];
    #pragma unroll
    for (int i = 0; i < 4; ++i)
        #pragma unroll
        for (int j = 0; j < 4; ++j) acc[i][j] = (f32x4){0.f, 0.f, 0.f, 0.f};

    _Float16* As = smem;
    _Float16* Bs = smem + 8192;
    const int sub = lane >> 3;
    const int swc = (lane & 7) ^ sub;
    const _Float16* agl = Ab + (size_t)(wv * 32 + sub) * DD + swc * 8;
    const _Float16* bgl = Bb + (size_t)(wv * 32 + sub) * DD + swc * 8;

    for (int kb = 0; kb < DD / 64; ++kb) {
        const int k0 = kb * 64;
        #pragma unroll
        for (int c = 0; c < 4; ++c) {
            async_ld16(&As[(wv * 32 + c * 8) * 64], agl + (size_t)c * 8 * DD + k0);
            async_ld16(&Bs[(wv * 32 + c * 8) * 64], bgl + (size_t)c * 8 * DD + k0);
        }
        __syncthreads();
        #pragma unroll
        for (int kc = 0; kc < 2; ++kc) {
            f16x8 af[4], bf[4];
            #pragma unroll
            for (int t = 0; t < 4; ++t) {
                const int Ra = wr * 64 + t * 16 + m_;
                const int Rb = wc * 64 + t * 16 + m_;
                af[t] = *(const f16x8*)&As[Ra * 64 + (((kc * 4 + quad) ^ (Ra & 7)) * 8)];
                bf[t] = *(const f16x8*)&Bs[Rb * 64 + (((kc * 4 + quad) ^ (Rb & 7)) * 8)];
            }
            #pragma unroll
            for (int i = 0; i < 4; ++i)
                #pragma unroll
                for (int j = 0; j < 4; ++j)
                    acc[i][j] = __builtin_amdgcn_mfma_f32_16x16x32_f16(af[i], bf[j], acc[i][j], 0, 0, 0);
        }
        __syncthreads();
    }

    // Epilogue: scale + exp into packed f16x4; register row/col sums.
    f16x4 wq[4][4];
    float rowpart[4][4];
    float colpart[4] = {0.f, 0.f, 0.f, 0.f};
    #pragma unroll
    for (int i = 0; i < 4; ++i)
        #pragma unroll
        for (int r = 0; r < 4; ++r) rowpart[i][r] = 0.f;

    #pragma unroll
    for (int i = 0; i < 4; ++i) {
        const int rowb = wr * 64 + i * 16 + quad * 4;
        #pragma unroll
        for (int j = 0; j < 4; ++j) {
            const int col = wc * 64 + j * 16 + m_;
            const float rj = rnJ[col];
            #pragma unroll
            for (int r = 0; r < 4; ++r) {
                const float w = __expf(acc[i][j][r] * rnI[rowb + r] * rj);
                wq[i][j][r] = (_Float16)w;
                rowpart[i][r] += w;
                colpart[j] += w;
            }
        }
    }

    #pragma unroll
    for (int i = 0; i < 4; ++i) {
        #pragma unroll
        for (int r = 0; r < 4; ++r) {
            float s = rowpart[i][r];
            s += __shfl_xor(s, 1);
            s += __shfl_xor(s, 2);
            s += __shfl_xor(s, 4);
            s += __shfl_xor(s, 8);
            if (m_ == 0)
                atomicAdd(&denom[b * NN + I + wr * 64 + i * 16 + quad * 4 + r], s);
        }
    }
    if (!diag) {
        #pragma unroll
        for (int j = 0; j < 4; ++j) {
            float s = colpart[j];
            s += __shfl_xor(s, 16);
            s += __shfl_xor(s, 32);
            if (quad == 0)
                atomicAdd(&denom[b * NN + J + wc * 64 + j * 16 + m_], s);
        }
    }

    // Phase 1: WtT[col][row] pitch 136, b64 writes -> coalesced W(J,I).
    _Float16* WtT = smem;
    #pragma unroll
    for (int i = 0; i < 4; ++i) {
        const int rowb = wr * 64 + i * 16 + quad * 4;
        #pragma unroll
        for (int j = 0; j < 4; ++j) {
            const int col = wc * 64 + j * 16 + m_;
            *(f16x4*)&WtT[col * 136 + rowb] = wq[i][j];
        }
    }
    __syncthreads();
    {
        const int rr = tid >> 1, off = (tid & 1) * 64;
        _Float16* wg = W + ((size_t)b * NN + J + rr) * NN + I + off;
        const _Float16* wl = &WtT[rr * 136 + off];
        #pragma unroll
        for (int c = 0; c < 64; c += 8)
            *(uint4*)(wg + c) = *(const uint4*)(wl + c);
    }
    // Phase 2 (off-diag): row-major Wt pitch 130 -> coalesced W(I,J).
    if (!diag) {
        __syncthreads();
        _Float16* Wt = smem;
        #pragma unroll
        for (int i = 0; i < 4; ++i) {
            const int rowb = wr * 64 + i * 16 + quad * 4;
            #pragma unroll
            for (int j = 0; j < 4; ++j) {
                const int col = wc * 64 + j * 16 + m_;
                #pragma unroll
                for (int r = 0; r < 4; ++r)
                    Wt[(rowb + r) * 130 + col] = wq[i][j][r];
            }
        }
        __syncthreads();
        const int rr = tid >> 1, off = (tid & 1) * 64;
        _Float16* wg = W + ((size_t)b * NN + I + rr) * NN + J + off;
        const _Float16* wl = &Wt[rr * 130 + off];
        #pragma unroll
        for (int c = 0; c < 64; c += 8)
            *(uint4*)(wg + c) = *(const uint4*)(wl + c);
    }
}

// ---------------------------------------------------------------------------
// K3: O = (W @ V) * (1/denom_i), fp32 out.  [R3 structure — known 123 us]
// ---------------------------------------------------------------------------
__global__ __launch_bounds__(256) void k_pv(const _Float16* __restrict__ W,
                                            const _Float16* __restrict__ vT,
                                            const float* __restrict__ denom,
                                            float* __restrict__ out) {
    __shared__ _Float16 smem[16384];          // As[8192] Bs[8192]
    __shared__ float rdI[128];
    const int tid = threadIdx.x;
    const int lane = tid & 63, wv = tid >> 6;
    const int wr = wv >> 1, wc = wv & 1;
    const int m_ = lane & 15, quad = lane >> 4;
    const int rm = m_ & 7;
    const int b = blockIdx.z;
    const int I = blockIdx.x * 128;
    const int D0 = blockIdx.y * 128;
    const _Float16* Ab = W + ((size_t)b * NN + I) * NN;
    const _Float16* Bb = vT + ((size_t)b * DD + D0) * NN;
    if (tid < 128) rdI[tid] = 1.0f / denom[b * NN + I + tid];

    f32x4 acc[4][4];
    #pragma unroll
    for (int i = 0; i < 4; ++i)
        #pragma unroll
        for (int j = 0; j < 4; ++j) acc[i][j] = (f32x4){0.f, 0.f, 0.f, 0.f};

    _Float16* As = smem;
    _Float16* Bs = smem + 8192;

    const int sub = lane >> 3;
    const int swc = (lane & 7) ^ sub;
    const _Float16* agl = Ab + (size_t)(wv * 32 + sub) * NN + swc * 8;
    const _Float16* bgl = Bb + (size_t)(wv * 32 + sub) * NN + swc * 8;

    for (int kb = 0; kb < NN / 64; ++kb) {
        const int k0 = kb * 64;
        #pragma unroll
        for (int c = 0; c < 4; ++c) {
            async_ld16(&As[(wv * 32 + c * 8) * 64], agl + (size_t)c * 8 * NN + k0);
            async_ld16(&Bs[(wv * 32 + c * 8) * 64], bgl + (size_t)c * 8 * NN + k0);
        }
        __syncthreads();
        #pragma unroll
        for (int kc = 0; kc < 2; ++kc) {
            f16x8 af[4], bf[4];
            #pragma unroll
            for (int t = 0; t < 4; ++t) {
                const int ko = ((kc * 4 + quad) ^ rm) * 8;
                af[t] = *(const f16x8*)&As[(wr * 64 + t * 16 + m_) * 64 + ko];
                bf[t] = *(const f16x8*)&Bs[(wc * 64 + t * 16 + m_) * 64 + ko];
            }
            #pragma unroll
            for (int i = 0; i < 4; ++i)
                #pragma unroll
                for (int j = 0; j < 4; ++j)
                    acc[i][j] = __builtin_amdgcn_mfma_f32_16x16x32_f16(af[i], bf[j], acc[i][j], 0, 0, 0);
        }
        __syncthreads();
    }

    #pragma unroll
    for (int i = 0; i < 4; ++i) {
        const int rowb = wr * 64 + i * 16 + quad * 4;
        #pragma unroll
        for (int r = 0; r < 4; ++r) {
            const float sc = rdI[rowb + r];
            float* op = out + ((size_t)(b * NN + I + rowb + r)) * DD + D0;
            #pragma unroll
            for (int j = 0; j < 4; ++j)
                op[wc * 64 + j * 16 + m_] = acc[i][j][r] * sc;
        }
    }
}

// ---------------------------------------------------------------------------
extern "C" void kernel_launch(void* const* d_in, const int* in_sizes, int n_in,
                              void* d_out, int out_size, void* d_ws, size_t ws_size,
                              hipStream_t stream) {
    const float* x = (const float*)d_in[0];
    char* ws = (char*)d_ws;
    _Float16* xh    = (_Float16*)(ws);                        // 32 MiB fp16 (unnormalized)
    _Float16* vT    = (_Float16*)(ws + (size_t)33554432);     // 32 MiB fp16 x^T
    _Float16* W     = (_Float16*)(ws + (size_t)67108864);     // 128 MiB fp16 exp-scores
    float*    rnorm = (float*)   (ws + (size_t)201326592);    // 128 KiB
    float*    denom = (float*)   (ws + (size_t)201457664);    // 128 KiB
    float*    out   = (float*)d_out;

    k_prep<<<dim3(NN / 64, BB), 256, 0, stream>>>(x, xh, vT, rnorm, denom);
    const int npairs = (NN / 128) * (NN / 128 + 1) / 2;   // 136
    k_scores<<<dim3(npairs, 1, BB), 256, 0, stream>>>(xh, rnorm, W, denom);
    k_pv<<<dim3(NN / 128, DD / 128, BB), 256, 0, stream>>>(W, vT, denom, out);
}